// Round 11
// baseline (125.067 us; speedup 1.0000x reference)
//
#include <hip/hip_runtime.h>

#define BB 128
#define LL 336
#define CC 862
#define PRED 96
#define WIN 12
#define S_IN 28
#define S_OUT 8
#define NQ 7
#define CT 32
#define NTILES ((CC + CT - 1) / CT)   // 27

#define SQRT12F 3.4641016151377544f

// -Sb(t)/sqrt(12), Sb(t) = 2*sum_{k=1..5} sin(pi*k*t/6)   (exact closed forms)
__device__ const float COEFP[12] = {
    0.0f, -2.1547005383792515f, 0.0f, -0.5773502691896258f,
    0.0f, -0.15470053837925146f, 0.0f, 0.15470053837925146f,
    0.0f,  0.5773502691896258f, 0.0f,  2.1547005383792515f
};

// ---- prep kernels ----

// repacked layout: wX4[((q*S_OUT + p)*CC + c)*4 + j] = wX[c][p][4q+j]
// -> thread (c,p) reads its 7 float4s at float4-index (q*8+p)*CC + c  (coalesced over c)
__global__ void prep_w4(const float* __restrict__ wA, const float* __restrict__ wP,
                        float* __restrict__ wA4, float* __restrict__ wP4) {
    int i = blockIdx.x * 256 + threadIdx.x;
    if (i >= NQ * S_OUT * CC * 4) return;
    int j  = i & 3;
    int c  = (i >> 2) % CC;
    int p  = (i / (4 * CC)) % S_OUT;
    int q  = i / (4 * CC * S_OUT);
    int s  = 4 * q + j;
    int src = (c * S_OUT + p) * S_IN + s;
    wA4[i] = wA[src];
    wP4[i] = wP[src];
}

__global__ void prep_mcoef(const float* __restrict__ wA, float* __restrict__ mcoefT) {
    int i = blockIdx.x * 256 + threadIdx.x;          // [p][c]
    if (i >= S_OUT * CC) return;
    int c = i % CC;
    int p = i / CC;
    float s = 0.f;
    for (int k = 0; k < S_IN; ++k) s += wA[(c * S_OUT + p) * S_IN + k];
    mcoefT[i] = 1.0f - s;
}

__global__ void prep_bias(const float* __restrict__ bA, const float* __restrict__ bP,
                          float* __restrict__ biasv) {
    int i = blockIdx.x * 256 + threadIdx.x;          // [t][p][c]
    if (i >= 12 * S_OUT * CC) return;
    int c = i % CC;
    int tp = i / CC;
    int p = tp % S_OUT;
    int t = tp / S_OUT;
    float v = COEFP[t] * bP[c * S_OUT + p];
    if (t == 0) v += SQRT12F * bA[c * S_OUT + p];
    biasv[i] = v;
}

// ---- fused main kernel: thread = (cc, p). x staged in LDS; ALL weights in
//      registers via 14 float4 loads issued BEFORE the staging sync (latency
//      hidden under fill); hot loop = pure LDS broadcast + FMA. q-loop fully
//      unrolled so weight-register indexing is compile-time (rule #20). ----

template <bool TRANS>
__global__ __launch_bounds__(256, 4) void fused11(
    const float* __restrict__ x,
    const float* __restrict__ wA4, const float* __restrict__ wP4,
    const float* __restrict__ mcoefT, const float* __restrict__ biasv,
    const float* __restrict__ wA_raw, const float* __restrict__ wP_raw,
    const float* __restrict__ bAr, const float* __restrict__ bPr,
    float* __restrict__ out)
{
    __shared__ float sx[LL][CT];      // 43008 B

    const int b   = blockIdx.y;
    const int c0  = blockIdx.x * CT;
    const int NC  = min(CT, CC - c0); // 32 or 30 (always even)
    const int tid = threadIdx.x;
    const int cc  = tid & 31;
    const int p   = tid >> 5;            // 0..7
    const int c   = c0 + cc;
    const bool wrOK = (cc < NC);
    const int cl  = wrOK ? c : (CC - 1); // clamped for global loads

    // ---- issue weight loads FIRST (independent of staging; latency hides under it)
    float4 wa4[NQ], wp4[NQ];
    if (TRANS) {
        const float4* wa = reinterpret_cast<const float4*>(wA4) + (size_t)p * CC + cl;
        const float4* wp = reinterpret_cast<const float4*>(wP4) + (size_t)p * CC + cl;
        #pragma unroll
        for (int q = 0; q < NQ; ++q) {
            wa4[q] = wa[(size_t)(q * S_OUT) * CC];
            wp4[q] = wp[(size_t)(q * S_OUT) * CC];
        }
    } else {
        const float* wa = wA_raw + (size_t)(cl * S_OUT + p) * S_IN;
        const float* wp = wP_raw + (size_t)(cl * S_OUT + p) * S_IN;
        #pragma unroll
        for (int q = 0; q < NQ; ++q) {
            wa4[q] = make_float4(wa[4*q], wa[4*q+1], wa[4*q+2], wa[4*q+3]);
            wp4[q] = make_float4(wp[4*q], wp[4*q+1], wp[4*q+2], wp[4*q+3]);
        }
    }

    // ---- stage x[b, :, c0:c0+NC]: 21 independent float2 loads/thread ----
    {
        const int jj  = tid & 15;
        const int r0  = tid >> 4;        // 0..15
        const int col = 2 * jj;
        const int csrc = (col + 1 < NC) ? col : (NC - 2);
        const float* base = x + ((size_t)b * LL) * CC + c0 + csrc;
        #pragma unroll
        for (int k = 0; k < 21; ++k) {
            const int r = r0 + k * 16;
            const float2 v = *reinterpret_cast<const float2*>(base + (size_t)r * CC);
            sx[r][col]     = v.x;
            sx[r][col + 1] = v.y;
        }
    }
    __syncthreads();

    float A0 = 0.f, A6 = 0.f;
    float Au[5] = {0.f, 0.f, 0.f, 0.f, 0.f};
    float Pv[5] = {0.f, 0.f, 0.f, 0.f, 0.f};
    float msum = 0.f;

    #pragma unroll
    for (int q = 0; q < NQ; ++q) {
        #pragma unroll
        for (int j = 0; j < 4; ++j) {
            const int s = 4 * q + j;
            const float wa = (j == 0) ? wa4[q].x : (j == 1) ? wa4[q].y : (j == 2) ? wa4[q].z : wa4[q].w;
            const float wp = (j == 0) ? wp4[q].x : (j == 1) ? wp4[q].y : (j == 2) ? wp4[q].z : wp4[q].w;

            float x12[12];
            #pragma unroll
            for (int t = 0; t < 12; ++t) x12[t] = sx[s * WIN + t][cc];

            A0 = fmaf(wa, x12[0], A0);
            A6 = fmaf(wa, x12[6], A6);
            float usum = x12[0] + x12[6];
            #pragma unroll
            for (int t = 1; t <= 5; ++t) {
                const float uu = x12[t] + x12[12 - t];
                const float vv = x12[t] - x12[12 - t];
                Au[t - 1] = fmaf(wa, uu, Au[t - 1]);
                Pv[t - 1] = fmaf(wp, vv, Pv[t - 1]);
                usum += uu;
            }
            msum += usum;
        }
    }

    if (!wrOK) return;

    const float mean = msum * (1.0f / LL);

    float mc, bias[12];
    if (TRANS) {
        mc = mcoefT[p * CC + c];
        #pragma unroll
        for (int t = 0; t < 12; ++t) bias[t] = biasv[(size_t)(t * S_OUT + p) * CC + c];
    } else {
        float sw = 0.f;
        #pragma unroll
        for (int q = 0; q < NQ; ++q)
            sw += (wa4[q].x + wa4[q].y) + (wa4[q].z + wa4[q].w);
        mc = 1.0f - sw;
        const float ba = bAr[c * S_OUT + p], bp = bPr[c * S_OUT + p];
        #pragma unroll
        for (int t = 0; t < 12; ++t) {
            bias[t] = COEFP[t] * bp + (t == 0 ? SQRT12F * ba : 0.f);
        }
    }

    const float mb = mean * mc;
    float* ob = out + ((size_t)b * PRED + p * WIN) * CC + c;

    ob[0]               = A0 + mb + bias[0];
    ob[(size_t)6 * CC]  = A6 + mb + bias[6];
    #pragma unroll
    for (int t = 1; t <= 5; ++t) {
        ob[(size_t)t * CC]        = 0.5f * (Au[t-1] + Pv[t-1]) + mb + bias[t];
        ob[(size_t)(12 - t) * CC] = 0.5f * (Au[t-1] - Pv[t-1]) + mb + bias[12 - t];
    }
}

extern "C" void kernel_launch(void* const* d_in, const int* in_sizes, int n_in,
                              void* d_out, int out_size, void* d_ws, size_t ws_size,
                              hipStream_t stream) {
    const float* x  = (const float*)d_in[0];
    const float* wA = (const float*)d_in[1];
    const float* bA = (const float*)d_in[2];
    const float* wP = (const float*)d_in[3];
    const float* bP = (const float*)d_in[4];
    float* out = (float*)d_out;

    const size_t nW  = (size_t)NQ * S_OUT * CC * 4;  // 193088
    const size_t nM  = (size_t)S_OUT * CC;           // 6896
    const size_t nBv = (size_t)12 * S_OUT * CC;      // 82752
    const size_t need = (2 * nW + nM + nBv) * sizeof(float);

    dim3 grid(NTILES, BB);

    if (ws_size >= need) {
        float* wA4    = (float*)d_ws;
        float* wP4    = wA4 + nW;
        float* mcoefT = wP4 + nW;
        float* biasv  = mcoefT + nM;

        prep_w4<<<(int)((nW + 255) / 256), 256, 0, stream>>>(wA, wP, wA4, wP4);
        prep_mcoef<<<(int)((nM + 255) / 256), 256, 0, stream>>>(wA, mcoefT);
        prep_bias<<<(int)((nBv + 255) / 256), 256, 0, stream>>>(bA, bP, biasv);

        fused11<true><<<grid, 256, 0, stream>>>(
            x, wA4, wP4, mcoefT, biasv,
            nullptr, nullptr, nullptr, nullptr, out);
    } else {
        fused11<false><<<grid, 256, 0, stream>>>(
            x, nullptr, nullptr, nullptr, nullptr,
            wA, wP, bA, bP, out);
    }
}

// Round 12
// 85.282 us; speedup vs baseline: 1.4665x; 1.4665x over previous
//
#include <hip/hip_runtime.h>

#define BB 128
#define LL 336
#define CC 862
#define PRED 96
#define WIN 12
#define S_IN 28
#define S_OUT 8
#define CT 32
#define RS 340                         // padded LDS row stride (dwords): 336 + 4
#define NTILES ((CC + CT - 1) / CT)   // 27

#define SQRT12F 3.4641016151377544f

// -Sb(t)/sqrt(12), Sb(t) = 2*sum_{k=1..5} sin(pi*k*t/6)   (exact closed forms)
__device__ const float COEFP[12] = {
    0.0f, -2.1547005383792515f, 0.0f, -0.5773502691896258f,
    0.0f, -0.15470053837925146f, 0.0f, 0.15470053837925146f,
    0.0f,  0.5773502691896258f, 0.0f,  2.1547005383792515f
};

// ---- prep kernels ----

// wXT layout: [p][s][c]  (c contiguous -> coalesced per-lane weight reads)
__global__ void prep_wT(const float* __restrict__ wA, const float* __restrict__ wP,
                        float* __restrict__ wAT, float* __restrict__ wPT) {
    int i = blockIdx.x * 256 + threadIdx.x;          // i = (p*S_IN + s)*CC + c
    if (i >= S_OUT * S_IN * CC) return;
    int c  = i % CC;
    int ps = i / CC;
    int s  = ps % S_IN;
    int p  = ps / S_IN;
    int src = (c * S_OUT + p) * S_IN + s;
    wAT[i] = wA[src];
    wPT[i] = wP[src];
}

__global__ void prep_mcoef(const float* __restrict__ wA, float* __restrict__ mcoefT) {
    int i = blockIdx.x * 256 + threadIdx.x;          // [p][c]
    if (i >= S_OUT * CC) return;
    int c = i % CC;
    int p = i / CC;
    float s = 0.f;
    for (int k = 0; k < S_IN; ++k) s += wA[(c * S_OUT + p) * S_IN + k];
    mcoefT[i] = 1.0f - s;
}

__global__ void prep_bias(const float* __restrict__ bA, const float* __restrict__ bP,
                          float* __restrict__ biasv) {
    int i = blockIdx.x * 256 + threadIdx.x;          // [t][p][c]
    if (i >= 12 * S_OUT * CC) return;
    int c = i % CC;
    int tp = i / CC;
    int p = tp % S_OUT;
    int t = tp / S_OUT;
    float v = COEFP[t] * bP[c * S_OUT + p];
    if (t == 0) v += SQRT12F * bA[c * S_OUT + p];
    biasv[i] = v;
}

// ---- fused main kernel: thread = (cc, p). x staged TRANSPOSED in LDS
//      (sxT[cc][340]); compute reads 3x ds_read_b128 per s (84 LDS reads
//      vs fused10's 336 scalar b32 -> the measured LDS-issue bottleneck).
//      Weights in-loop (fused10's scheme: VGPR stays ~68). ----

template <bool TRANS>
__global__ __launch_bounds__(256) void fused12(
    const float* __restrict__ x,
    const float* __restrict__ wAT, const float* __restrict__ wPT,
    const float* __restrict__ mcoefT, const float* __restrict__ biasv,
    const float* __restrict__ wA_raw, const float* __restrict__ wP_raw,
    const float* __restrict__ bAr, const float* __restrict__ bPr,
    float* __restrict__ out)
{
    __shared__ __align__(16) float sxT[CT * RS];   // 43520 B

    const int b   = blockIdx.y;
    const int c0  = blockIdx.x * CT;
    const int NC  = min(CT, CC - c0); // 32 or 30 (always even)
    const int tid = threadIdx.x;

    // ---- stage x[b, :, c0:c0+NC] transposed: float2 global, 2x b32 LDS scatter ----
    {
        const int jj  = tid & 15;        // float2 slot in row
        const int r0  = tid >> 4;        // 0..15
        const int col = 2 * jj;
        const int csrc = (col + 1 < NC) ? col : (NC - 2);   // NC even, >=2
        const float* base = x + ((size_t)b * LL) * CC + c0 + csrc;
        float* d0 = sxT + col * RS;
        float* d1 = sxT + (col + 1) * RS;
        #pragma unroll
        for (int k = 0; k < 21; ++k) {
            const int r = r0 + k * 16;
            const float2 v = *reinterpret_cast<const float2*>(base + (size_t)r * CC);
            d0[r] = v.x;
            d1[r] = v.y;
        }
    }
    __syncthreads();

    const int cc = tid & 31;
    const int p  = tid >> 5;             // 0..7, all active
    const int c  = c0 + cc;
    const bool wrOK = (cc < NC);
    const int cl = wrOK ? c : (CC - 1);  // clamped for global weight loads

    float A0 = 0.f, A6 = 0.f;
    float Au[5] = {0.f, 0.f, 0.f, 0.f, 0.f};
    float Pv[5] = {0.f, 0.f, 0.f, 0.f, 0.f};
    float msum = 0.f;
    float sw = 0.f;                      // fallback: sum of wA over s

    const float* xrow = sxT + cc * RS;

    #pragma unroll 4
    for (int s = 0; s < S_IN; ++s) {
        float wa, wp;
        if (TRANS) {
            wa = wAT[(size_t)(p * S_IN + s) * CC + cl];
            wp = wPT[(size_t)(p * S_IN + s) * CC + cl];
        } else {
            wa = wA_raw[(size_t)(cl * S_OUT + p) * S_IN + s];
            wp = wP_raw[(size_t)(cl * S_OUT + p) * S_IN + s];
            sw += wa;
        }
        const float4 xa = *reinterpret_cast<const float4*>(xrow + 12 * s);      // t0..3
        const float4 xb = *reinterpret_cast<const float4*>(xrow + 12 * s + 4);  // t4..7
        const float4 xc = *reinterpret_cast<const float4*>(xrow + 12 * s + 8);  // t8..11

        // pairs: (1,11)(2,10)(3,9)(4,8)(5,7); singles 0,6
        const float u1 = xa.y + xc.w;
        const float u2 = xa.z + xc.z;
        const float u3 = xa.w + xc.y;
        const float u4 = xb.x + xc.x;
        const float u5 = xb.y + xb.w;
        const float v1 = xa.y - xc.w;
        const float v2 = xa.z - xc.z;
        const float v3 = xa.w - xc.y;
        const float v4 = xb.x - xc.x;
        const float v5 = xb.y - xb.w;

        A0 = fmaf(wa, xa.x, A0);
        A6 = fmaf(wa, xb.z, A6);
        Au[0] = fmaf(wa, u1, Au[0]);
        Au[1] = fmaf(wa, u2, Au[1]);
        Au[2] = fmaf(wa, u3, Au[2]);
        Au[3] = fmaf(wa, u4, Au[3]);
        Au[4] = fmaf(wa, u5, Au[4]);
        Pv[0] = fmaf(wp, v1, Pv[0]);
        Pv[1] = fmaf(wp, v2, Pv[1]);
        Pv[2] = fmaf(wp, v3, Pv[2]);
        Pv[3] = fmaf(wp, v4, Pv[3]);
        Pv[4] = fmaf(wp, v5, Pv[4]);

        msum += (xa.x + xb.z) + ((u1 + u2) + (u3 + u4) + u5);
    }

    if (!wrOK) return;

    const float mean = msum * (1.0f / LL);

    float mc, bias[12];
    if (TRANS) {
        mc = mcoefT[p * CC + c];
        #pragma unroll
        for (int t = 0; t < 12; ++t) bias[t] = biasv[(size_t)(t * S_OUT + p) * CC + c];
    } else {
        mc = 1.0f - sw;
        const float ba = bAr[c * S_OUT + p], bp = bPr[c * S_OUT + p];
        #pragma unroll
        for (int t = 0; t < 12; ++t) {
            bias[t] = COEFP[t] * bp + (t == 0 ? SQRT12F * ba : 0.f);
        }
    }

    const float mb = mean * mc;
    float* ob = out + ((size_t)b * PRED + p * WIN) * CC + c;

    ob[0]               = A0 + mb + bias[0];
    ob[(size_t)6 * CC]  = A6 + mb + bias[6];
    #pragma unroll
    for (int t = 1; t <= 5; ++t) {
        ob[(size_t)t * CC]        = 0.5f * (Au[t-1] + Pv[t-1]) + mb + bias[t];
        ob[(size_t)(12 - t) * CC] = 0.5f * (Au[t-1] - Pv[t-1]) + mb + bias[12 - t];
    }
}

extern "C" void kernel_launch(void* const* d_in, const int* in_sizes, int n_in,
                              void* d_out, int out_size, void* d_ws, size_t ws_size,
                              hipStream_t stream) {
    const float* x  = (const float*)d_in[0];
    const float* wA = (const float*)d_in[1];
    const float* bA = (const float*)d_in[2];
    const float* wP = (const float*)d_in[3];
    const float* bP = (const float*)d_in[4];
    float* out = (float*)d_out;

    const size_t nW  = (size_t)S_OUT * S_IN * CC;    // 193088
    const size_t nM  = (size_t)S_OUT * CC;           // 6896
    const size_t nBv = (size_t)12 * S_OUT * CC;      // 82752
    const size_t need = (2 * nW + nM + nBv) * sizeof(float);

    dim3 grid(NTILES, BB);

    if (ws_size >= need) {
        float* wAT    = (float*)d_ws;
        float* wPT    = wAT + nW;
        float* mcoefT = wPT + nW;
        float* biasv  = mcoefT + nM;

        prep_wT<<<(int)((nW + 255) / 256), 256, 0, stream>>>(wA, wP, wAT, wPT);
        prep_mcoef<<<(int)((nM + 255) / 256), 256, 0, stream>>>(wA, mcoefT);
        prep_bias<<<(int)((nBv + 255) / 256), 256, 0, stream>>>(bA, bP, biasv);

        fused12<true><<<grid, 256, 0, stream>>>(
            x, wAT, wPT, mcoefT, biasv,
            nullptr, nullptr, nullptr, nullptr, out);
    } else {
        fused12<false><<<grid, 256, 0, stream>>>(
            x, nullptr, nullptr, nullptr, nullptr,
            wA, wP, bA, bP, out);
    }
}